// Round 17
// baseline (218.247 us; speedup 1.0000x reference)
//
#include <hip/hip_runtime.h>
#include <hip/hip_bf16.h>
#include <math.h>
#include <stdint.h>

typedef __attribute__((ext_vector_type(8))) short short8;
typedef __attribute__((ext_vector_type(4))) float f32x4;

#define BM 256
#define NKT 36
#define A_BYTES (BM * 128)          // 32 KiB per A buffer
#define LDS_TOTAL (4 * A_BYTES)     // 128 KiB: 4-buffer A ring

__device__ __forceinline__ unsigned short f2bf(float f) {
    __bf16 h = (__bf16)f;
    return __builtin_bit_cast(unsigned short, h);
}

__device__ __forceinline__ float gelu_exact(float x) {
    return 0.5f * x * (1.0f + erff(x * 0.7071067811865475f));
}

// swizzled byte offset for 16B unit u of a 64-bf16 (128B) LDS row
__device__ __forceinline__ int swz(int row, int u) {
    return row * 128 + ((u ^ (row & 7)) << 4);
}

// Frag-major, per-lane-CONTIGUOUS weight image (verified R16): 16B unit
// U = kt*2048 + wc*512 + lane*8 + i, i = kh*4 + n.
// Unit holds W[o][k0..k0+8) with o = wc*64 + n*16 + (lane&15),
// k0 = kt*64 + (kh*4 + (lane>>4))*8.
__global__ void kan_prep_w(const float* __restrict__ bw, const float* __restrict__ sw,
                           unsigned short* __restrict__ Wf) {
    int U = blockIdx.x * 256 + threadIdx.x;   // 36*2048 units
    if (U >= NKT * 2048) return;
    int kt = U >> 11, rem = U & 2047;
    int wcq = rem >> 9, rem2 = rem & 511;
    int lane = rem2 >> 3, i = rem2 & 7;
    int n = i & 3, kh = i >> 2;
    int o = wcq * 64 + n * 16 + (lane & 15);
    int k0 = kt * 64 + (kh * 4 + (lane >> 4)) * 8;
    unsigned short pk[8];
#pragma unroll
    for (int e = 0; e < 8; ++e) {
        int kk = k0 + e;
        float v = (kk < 256) ? bw[o * 256 + kk] : sw[o * 2048 + (kk - 256)];
        pk[e] = f2bf(v);
    }
    *(short8*)(Wf + (size_t)U * 8) = *(short8*)pk;
}

// spline: 16B row image (8 bf16 slots, 4 nonzero) via funnel shift (verified R2)
__device__ __forceinline__ short8 spline_row(float xv) {
    float xi = (xv + 2.2f) * 2.5f;
    float fi = floorf(xi);
    float tt = xi - fi;
    float s1 = 1.0f - tt;
    float t2 = tt * tt, t3 = t2 * tt;
    float w0 = s1 * s1 * s1 * (1.0f / 6.0f);
    float w1 = 0.5f * t3 - t2 + (2.0f / 3.0f);
    float w2 = -0.5f * t3 + 0.5f * t2 + 0.5f * tt + (1.0f / 6.0f);
    float w3 = t3 * (1.0f / 6.0f);
    uint64_t Wp = (uint64_t)f2bf(w0) | ((uint64_t)f2bf(w1) << 16)
                | ((uint64_t)f2bf(w2) << 32) | ((uint64_t)f2bf(w3) << 48);
    int b = 16 * ((int)fi - 3);
    uint64_t L = (b >= 0 && b < 64) ? (Wp << b)
               : ((b < 0 && b > -64) ? (Wp >> (-b)) : 0ull);
    uint64_t H = (b >= 64 && b < 128) ? (Wp << (b - 64))
               : ((b > 0 && b < 64) ? (Wp >> (64 - b)) : 0ull);
    union { uint64_t q[2]; short8 v; } rr;
    rr.q[0] = L; rr.q[1] = H;
    return rr.v;
}

__global__ __launch_bounds__(1024)   // 16 waves -> 4/SIMD naturally; NO occupancy attribute
void kan_fused(
    const float* __restrict__ X, const unsigned short* __restrict__ Wf,
    const float* __restrict__ gamma, const float* __restrict__ beta,
    const float* __restrict__ prelu_a, float* __restrict__ OUT)
{
    extern __shared__ __align__(16) unsigned char lds[];   // 4 x 32K A ring

    const int t = threadIdx.x;
    const int row0 = blockIdx.x * BM;
    const int wid = t >> 6, lane = t & 63;
    const int wr = wid >> 2, wc = wid & 3;      // 4 x 4 waves; wave tile 64x64
    const int lcol = lane & 15, q = lane >> 4;
    const int srow = t >> 2, sil = (t & 3) << 1;  // staging: 1 row, 2 units/thread

    f32x4 acc[4][4];
#pragma unroll
    for (int m = 0; m < 4; ++m)
#pragma unroll
        for (int n = 0; n < 4; ++n) acc[m][n] = (f32x4){0.f, 0.f, 0.f, 0.f};

    // per-lane W frag block: 8 units (128B) per K-tile; bump +2048 units/K-tile
    const short8* wp = (const short8*)(Wf + ((size_t)wc * 512 + lane * 8) * 8);

    // consumes tile in B (self-loads W per kh: wv4 live only within its half)
    auto mfma_tile = [&](unsigned char* B) {
#pragma unroll
        for (int kh = 0; kh < 2; ++kh) {
            short8 wv4[4];
#pragma unroll
            for (int n = 0; n < 4; ++n) wv4[n] = wp[kh * 4 + n];
            short8 af[4];
#pragma unroll
            for (int m = 0; m < 4; ++m)
                af[m] = *(const short8*)(B + swz(wr * 64 + m * 16 + lcol, kh * 4 + q));
#pragma unroll
            for (int m = 0; m < 4; ++m)
#pragma unroll
                for (int n = 0; n < 4; ++n)
                    acc[m][n] = __builtin_amdgcn_mfma_f32_16x16x32_bf16(
                        af[m], wv4[n], acc[m][n], 0, 0, 0);
        }
        wp += 2048;
    };
    auto spline_stage = [&](float (&xs)[2], unsigned char* D) {
#pragma unroll
        for (int rep = 0; rep < 2; ++rep)
            *(short8*)(D + swz(srow, sil + rep)) = spline_row(xs[rep]);
    };
    auto gelu_stage = [&](int kt, unsigned char* D) {
#pragma unroll
        for (int rep = 0; rep < 2; ++rep) {
            const float* xp = X + (size_t)(row0 + srow) * 256 + kt * 64 + (sil + rep) * 8;
            float4 v0 = *(const float4*)xp;
            float4 v1 = *(const float4*)(xp + 4);
            float vv[8] = {v0.x, v0.y, v0.z, v0.w, v1.x, v1.y, v1.z, v1.w};
            unsigned short pk[8];
#pragma unroll
            for (int jj = 0; jj < 8; ++jj) pk[jj] = f2bf(gelu_exact(vv[jj]));
            *(short8*)(D + swz(srow, sil + rep)) = *(short8*)pk;
        }
    };

    // ---- prologue: gelu tiles 0,1 -> slots 0,1 ----
    gelu_stage(0, lds);
    gelu_stage(1, lds + A_BYTES);
    asm volatile("s_waitcnt lgkmcnt(0)\n\ts_barrier" ::: "memory");

    // ---- main loop: 2 K-tiles per barrier, 4-buffer ring (R14 structure) ----
    for (int j = 0; j < NKT / 2; ++j) {
        const int ka = 2 * j;
        unsigned char* Ba = lds + (ka & 3) * A_BYTES;
        unsigned char* Bb = lds + ((ka + 1) & 3) * A_BYTES;
        unsigned char* Sa = lds + ((ka + 2) & 3) * A_BYTES;
        unsigned char* Sb = lds + ((ka + 3) & 3) * A_BYTES;
        const bool stg = (ka + 2 < NKT);
        const bool gA = (ka + 2 < 4), gB = (ka + 3 < 4);

        float xsA[2], xsB[2];
        if (stg && !gA) {
            const int ibA = (ka + 2 - 4) * 8;
#pragma unroll
            for (int rep = 0; rep < 2; ++rep)
                xsA[rep] = X[(size_t)(row0 + srow) * 256 + ibA + sil + rep];
        }
        if (stg && !gB) {
            const int ibB = (ka + 3 - 4) * 8;
#pragma unroll
            for (int rep = 0; rep < 2; ++rep)
                xsB[rep] = X[(size_t)(row0 + srow) * 256 + ibB + sil + rep];
        }

        mfma_tile(Ba);                 // W(ka) loaded per-kh inside
        if (stg) { if (gA) gelu_stage(ka + 2, Sa); else spline_stage(xsA, Sa); }
        mfma_tile(Bb);                 // W(ka+1)
        if (stg) { if (gB) gelu_stage(ka + 3, Sb); else spline_stage(xsB, Sb); }

        // one LDS-only barrier per 2 K-tiles (reg-targeted loads stay in flight)
        asm volatile("s_waitcnt lgkmcnt(0)\n\ts_barrier" ::: "memory");
    }

    // ---- fused LayerNorm + PReLU epilogue (R13-verified 1024-thread geometry) ----
    float* stats = (float*)lds;   // [256][8]: 4 col-partial sums, 4 col-partial sumsq
#pragma unroll
    for (int m = 0; m < 4; ++m) {
#pragma unroll
        for (int r = 0; r < 4; ++r) {
            float s = 0.f, s2 = 0.f;
#pragma unroll
            for (int n = 0; n < 4; ++n) { float v = acc[m][n][r]; s += v; s2 += v * v; }
#pragma unroll
            for (int msk = 1; msk < 16; msk <<= 1) {
                s  += __shfl_xor(s,  msk, 64);
                s2 += __shfl_xor(s2, msk, 64);
            }
            if ((lane & 15) == (m * 4 + r)) {
                int row = wr * 64 + m * 16 + q * 4 + r;
                stats[row * 8 + wc]     = s;
                stats[row * 8 + 4 + wc] = s2;
            }
        }
    }
    __syncthreads();

    const float apr = prelu_a[0];
    float gv[4], bv[4];
#pragma unroll
    for (int n = 0; n < 4; ++n) {
        int col = wc * 64 + n * 16 + lcol;
        gv[n] = gamma[col]; bv[n] = beta[col];
    }
#pragma unroll
    for (int m = 0; m < 4; ++m) {
#pragma unroll
        for (int r = 0; r < 4; ++r) {
            int row = wr * 64 + m * 16 + q * 4 + r;
            f32x4 sv = *(const f32x4*)(stats + row * 8);
            f32x4 qv = *(const f32x4*)(stats + row * 8 + 4);
            float mu  = (sv[0] + sv[1] + sv[2] + sv[3]) * (1.0f / 256.0f);
            float ex2 = (qv[0] + qv[1] + qv[2] + qv[3]) * (1.0f / 256.0f);
            float rs = rsqrtf(ex2 - mu * mu + 1e-5f);
            float* op = OUT + (size_t)(row0 + row) * 256;
#pragma unroll
            for (int n = 0; n < 4; ++n) {
                int col = wc * 64 + n * 16 + lcol;
                float y = (acc[m][n][r] - mu) * rs * gv[n] + bv[n];
                op[col] = (y >= 0.f) ? y : apr * y;
            }
        }
    }
}

extern "C" void kernel_launch(void* const* d_in, const int* in_sizes, int n_in,
                              void* d_out, int out_size, void* d_ws, size_t ws_size,
                              hipStream_t stream) {
    const float* x  = (const float*)d_in[0];
    // d_in[1] = grid knots (uniform linspace; constants folded into closed form)
    const float* bw = (const float*)d_in[2];
    const float* sw = (const float*)d_in[3];
    const float* g  = (const float*)d_in[4];
    const float* be = (const float*)d_in[5];
    const float* pa = (const float*)d_in[6];
    float* out = (float*)d_out;
    unsigned short* Wf = (unsigned short*)d_ws;   // 36*2048*16B frag-major contiguous

    hipFuncSetAttribute((const void*)kan_fused,
                        hipFuncAttributeMaxDynamicSharedMemorySize, LDS_TOTAL);

    const int Nrows = in_sizes[0] / 256;
    kan_prep_w<<<(NKT * 2048 + 255) / 256, 256, 0, stream>>>(bw, sw, Wf);
    kan_fused<<<Nrows / BM, 1024, LDS_TOTAL, stream>>>(x, Wf, g, be, pa, out);
}

// Round 18
// 135.159 us; speedup vs baseline: 1.6147x; 1.6147x over previous
//
#include <hip/hip_runtime.h>
#include <hip/hip_bf16.h>
#include <math.h>
#include <stdint.h>

typedef __attribute__((ext_vector_type(8))) short short8;
typedef __attribute__((ext_vector_type(4))) float f32x4;

#define BM 256
#define NKT 36
#define A_BYTES (BM * 128)          // 32 KiB per A buffer
#define LDS_TOTAL (4 * A_BYTES)     // 128 KiB: 4-buffer A ring

__device__ __forceinline__ unsigned short f2bf(float f) {
    __bf16 h = (__bf16)f;
    return __builtin_bit_cast(unsigned short, h);
}

__device__ __forceinline__ float gelu_exact(float x) {
    return 0.5f * x * (1.0f + erff(x * 0.7071067811865475f));
}

// swizzled byte offset for 16B unit u of a 64-bf16 (128B) LDS row
__device__ __forceinline__ int swz(int row, int u) {
    return row * 128 + ((u ^ (row & 7)) << 4);
}

// Frag-major weight image (verified R7/R14): 16B unit
// U = kt*2048 + wc*512 + i*64 + lane, i = kh*4 + n.
// Unit holds W[o][k0..k0+8) with o = wc*64 + n*16 + (lane&15),
// k0 = kt*64 + (kh*4 + (lane>>4))*8.
__global__ void kan_prep_w(const float* __restrict__ bw, const float* __restrict__ sw,
                           unsigned short* __restrict__ Wf) {
    int U = blockIdx.x * 256 + threadIdx.x;   // 36*2048 units
    if (U >= NKT * 2048) return;
    int kt = U >> 11, rem = U & 2047;
    int wcq = rem >> 9, rem2 = rem & 511;
    int i = rem2 >> 6;                 // kh*4 + n
    int lane = rem2 & 63;
    int o = wcq * 64 + (i & 3) * 16 + (lane & 15);
    int k0 = kt * 64 + ((i >> 2) * 4 + (lane >> 4)) * 8;
    unsigned short pk[8];
#pragma unroll
    for (int e = 0; e < 8; ++e) {
        int kk = k0 + e;
        float v = (kk < 256) ? bw[o * 256 + kk] : sw[o * 2048 + (kk - 256)];
        pk[e] = f2bf(v);
    }
    *(short8*)(Wf + (size_t)U * 8) = *(short8*)pk;
}

// spline: 16B row image (8 bf16 slots, 4 nonzero) via funnel shift (verified R2)
__device__ __forceinline__ short8 spline_row(float xv) {
    float xi = (xv + 2.2f) * 2.5f;
    float fi = floorf(xi);
    float tt = xi - fi;
    float s1 = 1.0f - tt;
    float t2 = tt * tt, t3 = t2 * tt;
    float w0 = s1 * s1 * s1 * (1.0f / 6.0f);
    float w1 = 0.5f * t3 - t2 + (2.0f / 3.0f);
    float w2 = -0.5f * t3 + 0.5f * t2 + 0.5f * tt + (1.0f / 6.0f);
    float w3 = t3 * (1.0f / 6.0f);
    uint64_t Wp = (uint64_t)f2bf(w0) | ((uint64_t)f2bf(w1) << 16)
                | ((uint64_t)f2bf(w2) << 32) | ((uint64_t)f2bf(w3) << 48);
    int b = 16 * ((int)fi - 3);
    uint64_t L = (b >= 0 && b < 64) ? (Wp << b)
               : ((b < 0 && b > -64) ? (Wp >> (-b)) : 0ull);
    uint64_t H = (b >= 64 && b < 128) ? (Wp << (b - 64))
               : ((b > 0 && b < 64) ? (Wp >> (64 - b)) : 0ull);
    union { uint64_t q[2]; short8 v; } rr;
    rr.q[0] = L; rr.q[1] = H;
    return rr.v;
}

__global__ __launch_bounds__(512)   // 8 waves = 2/SIMD; no occupancy pin (R8-R10 rule)
void kan_fused(
    const float* __restrict__ X, const unsigned short* __restrict__ Wf,
    const float* __restrict__ gamma, const float* __restrict__ beta,
    const float* __restrict__ prelu_a, float* __restrict__ OUT)
{
    extern __shared__ __align__(16) unsigned char lds[];   // 4 x 32K A ring

    const int t = threadIdx.x;
    const int row0 = blockIdx.x * BM;
    const int wid = t >> 6, lane = t & 63;
    const int wr = wid >> 2, wc = wid & 3;      // 2 x 4 waves; wave tile 128x64
    const int lcol = lane & 15, q = lane >> 4;
    const int srow = t >> 3, scol = t & 7;      // staging: 4 reps x 64 rows

    f32x4 acc[8][4];
#pragma unroll
    for (int m = 0; m < 8; ++m)
#pragma unroll
        for (int n = 0; n < 4; ++n) acc[m][n] = (f32x4){0.f, 0.f, 0.f, 0.f};

    const unsigned short* wlane = Wf + ((size_t)wc * 512 + lane) * 8;
    short8 wv[8];

    auto w_load = [&](int kt) {
        const unsigned short* wsrc = wlane + (size_t)kt * 2048 * 8;
#pragma unroll
        for (int i = 0; i < 8; ++i)
            wv[i] = *(const short8*)(wsrc + i * 512);
    };
    auto gelu_rep = [&](int kt, int r, unsigned char* D) {
        const float* xp = X + (size_t)(row0 + srow + r * 64) * 256 + kt * 64 + scol * 8;
        float4 v0 = *(const float4*)xp;
        float4 v1 = *(const float4*)(xp + 4);
        float vv[8] = {v0.x, v0.y, v0.z, v0.w, v1.x, v1.y, v1.z, v1.w};
        unsigned short pk[8];
#pragma unroll
        for (int jj = 0; jj < 8; ++jj) pk[jj] = f2bf(gelu_exact(vv[jj]));
        *(short8*)(D + swz(srow + r * 64, scol)) = *(short8*)pk;
    };
    // MFMA over one tile with 2 staging reps spliced between independent m-groups
    auto mfma_tile_st = [&](unsigned char* B, auto&& srep) {
#pragma unroll
        for (int kh = 0; kh < 2; ++kh) {
#pragma unroll
            for (int m = 0; m < 8; ++m) {
                short8 af = *(const short8*)(B + swz(wr * 128 + m * 16 + lcol, kh * 4 + q));
#pragma unroll
                for (int n = 0; n < 4; ++n)
                    acc[m][n] = __builtin_amdgcn_mfma_f32_16x16x32_bf16(
                        af, wv[kh * 4 + n], acc[m][n], 0, 0, 0);
                if (m == 5) srep(kh);   // rep 0 inside kh=0, rep 1 inside kh=1
            }
        }
    };

    // ---- prologue: W(0); gelu tiles 0,1 -> slots 0,1 ----
    w_load(0);
#pragma unroll
    for (int r = 0; r < 4; ++r) gelu_rep(0, r, lds);
#pragma unroll
    for (int r = 0; r < 4; ++r) gelu_rep(1, r, lds + A_BYTES);
    asm volatile("s_waitcnt lgkmcnt(0)\n\ts_barrier" ::: "memory");

    // ---- main loop: 2 K-tiles per barrier, 4-buffer ring (R14 structure) ----
    for (int j = 0; j < NKT / 2; ++j) {
        const int ka = 2 * j;
        unsigned char* Ba = lds + (ka & 3) * A_BYTES;
        unsigned char* Bb = lds + ((ka + 1) & 3) * A_BYTES;
        unsigned char* Sa = lds + ((ka + 2) & 3) * A_BYTES;
        unsigned char* Sb = lds + ((ka + 3) & 3) * A_BYTES;
        const bool stg = (ka + 2 < NKT);    // NKT even & ka even => covers ka+3 too
        const bool gA = (ka + 2 < 4), gB = (ka + 3 < 4);

        float xsA[4], xsB[4];
        if (stg && !gA) {
            const int ibA = (ka + 2 - 4) * 8;
#pragma unroll
            for (int rep = 0; rep < 4; ++rep)
                xsA[rep] = X[(size_t)(row0 + srow + rep * 64) * 256 + ibA + scol];
        }
        if (stg && !gB) {
            const int ibB = (ka + 3 - 4) * 8;
#pragma unroll
            for (int rep = 0; rep < 4; ++rep)
                xsB[rep] = X[(size_t)(row0 + srow + rep * 64) * 256 + ibB + scol];
        }

        // tile A: MFMA with Sa reps 0,1 spliced in
        mfma_tile_st(Ba, [&](int r) {
            if (stg) {
                if (gA) gelu_rep(ka + 2, r, Sa);
                else *(short8*)(Sa + swz(srow + r * 64, scol)) = spline_row(xsA[r]);
            }
        });
        w_load(ka + 1);                      // W(ka+1); covered by Sa reps 2,3 below
        if (stg) {
            if (gA) { gelu_rep(ka + 2, 2, Sa); gelu_rep(ka + 2, 3, Sa); }
            else {
                *(short8*)(Sa + swz(srow + 2 * 64, scol)) = spline_row(xsA[2]);
                *(short8*)(Sa + swz(srow + 3 * 64, scol)) = spline_row(xsA[3]);
            }
        }
        // tile B: MFMA with Sb reps 0,1 spliced in
        mfma_tile_st(Bb, [&](int r) {
            if (stg) {
                if (gB) gelu_rep(ka + 3, r, Sb);
                else *(short8*)(Sb + swz(srow + r * 64, scol)) = spline_row(xsB[r]);
            }
        });
        if (stg) w_load(ka + 2);             // W(ka+2); covered by Sb reps 2,3
        if (stg) {
            if (gB) { gelu_rep(ka + 3, 2, Sb); gelu_rep(ka + 3, 3, Sb); }
            else {
                *(short8*)(Sb + swz(srow + 2 * 64, scol)) = spline_row(xsB[2]);
                *(short8*)(Sb + swz(srow + 3 * 64, scol)) = spline_row(xsB[3]);
            }
        }
        // one LDS-only barrier per 2 K-tiles (reg-targeted loads stay in flight)
        asm volatile("s_waitcnt lgkmcnt(0)\n\ts_barrier" ::: "memory");
    }

    // ---- fused LayerNorm + PReLU epilogue (verified R7/R14) ----
    float* stats = (float*)lds;   // [256][8]: 4 col-partial sums, 4 col-partial sumsq
#pragma unroll
    for (int m = 0; m < 8; ++m) {
#pragma unroll
        for (int r = 0; r < 4; ++r) {
            float s = 0.f, s2 = 0.f;
#pragma unroll
            for (int n = 0; n < 4; ++n) { float v = acc[m][n][r]; s += v; s2 += v * v; }
#pragma unroll
            for (int msk = 1; msk < 16; msk <<= 1) {
                s  += __shfl_xor(s,  msk, 64);
                s2 += __shfl_xor(s2, msk, 64);
            }
            if ((lane & 15) == ((m * 4 + r) & 15)) {
                int row = wr * 128 + m * 16 + q * 4 + r;
                stats[row * 8 + wc]     = s;
                stats[row * 8 + 4 + wc] = s2;
            }
        }
    }
    __syncthreads();

    const float apr = prelu_a[0];
    float gv[4], bv[4];
#pragma unroll
    for (int n = 0; n < 4; ++n) {
        int col = wc * 64 + n * 16 + lcol;
        gv[n] = gamma[col]; bv[n] = beta[col];
    }
#pragma unroll
    for (int m = 0; m < 8; ++m) {
#pragma unroll
        for (int r = 0; r < 4; ++r) {
            int row = wr * 128 + m * 16 + q * 4 + r;
            f32x4 sv = *(const f32x4*)(stats + row * 8);
            f32x4 qv = *(const f32x4*)(stats + row * 8 + 4);
            float mu  = (sv[0] + sv[1] + sv[2] + sv[3]) * (1.0f / 256.0f);
            float ex2 = (qv[0] + qv[1] + qv[2] + qv[3]) * (1.0f / 256.0f);
            float rs = rsqrtf(ex2 - mu * mu + 1e-5f);
            float* op = OUT + (size_t)(row0 + row) * 256;
#pragma unroll
            for (int n = 0; n < 4; ++n) {
                int col = wc * 64 + n * 16 + lcol;
                float y = (acc[m][n][r] - mu) * rs * gv[n] + bv[n];
                op[col] = (y >= 0.f) ? y : apr * y;
            }
        }
    }
}

extern "C" void kernel_launch(void* const* d_in, const int* in_sizes, int n_in,
                              void* d_out, int out_size, void* d_ws, size_t ws_size,
                              hipStream_t stream) {
    const float* x  = (const float*)d_in[0];
    // d_in[1] = grid knots (uniform linspace; constants folded into closed form)
    const float* bw = (const float*)d_in[2];
    const float* sw = (const float*)d_in[3];
    const float* g  = (const float*)d_in[4];
    const float* be = (const float*)d_in[5];
    const float* pa = (const float*)d_in[6];
    float* out = (float*)d_out;
    unsigned short* Wf = (unsigned short*)d_ws;   // 36*2048*16B frag-major

    hipFuncSetAttribute((const void*)kan_fused,
                        hipFuncAttributeMaxDynamicSharedMemorySize, LDS_TOTAL);

    const int Nrows = in_sizes[0] / 256;
    kan_prep_w<<<(NKT * 2048 + 255) / 256, 256, 0, stream>>>(bw, sw, Wf);
    kan_fused<<<Nrows / BM, 512, LDS_TOTAL, stream>>>(x, Wf, g, be, pa, out);
}